// Round 17
// baseline (112.784 us; speedup 1.0000x reference)
//
#include <hip/hip_runtime.h>
#include <hip/hip_bf16.h>

typedef unsigned short u16;
typedef unsigned short ushort8v __attribute__((ext_vector_type(8)));
typedef __bf16 bf16x8 __attribute__((ext_vector_type(8)));
typedef float f32x4 __attribute__((ext_vector_type(4)));

#define NB 16   // batch
#define NK 32   // K slices
#define ND 256  // D
#define NL 256  // L1 == L2

__device__ __forceinline__ u16 f2bf(float f) {
    __hip_bfloat16 h = __float2bfloat16(f);
    return __builtin_bit_cast(u16, h);
}

// async global->LDS, 16B per lane; lds dst = wave-uniform base + lane*16
__device__ __forceinline__ void gload_lds16(const void* g, void* l) {
    __builtin_amdgcn_global_load_lds(
        (const __attribute__((address_space(1))) unsigned int*)g,
        (__attribute__((address_space(3))) unsigned int*)l, 16, 0, 0);
}

// Fragment-order layout for a 256x256 matrix X[r][c] (c = contraction dim):
//   buf[((rt*8 + ct)*64 + lane)*8 + (c&7)], rt=r>>4, ct=c>>5,
//   lane = (r&15) | (((c>>3)&3)<<4)
// => a wave's 16x16x32 MFMA fragment is 1 KiB contiguous; coalesced dwordx4 loads.

// ---------------- prep ----------------
// blocks 0..1023    : x1 f32 -> frag-order bf16 [l][d]
// blocks 1024..2047 : x2 f32 -> frag-order bf16 [m][e]
// blocks 2048..2303 : W  f32 -> frag-order bf16 of W^T, i.e. [e][d] (contraction d)
//                     via LDS-staged transpose: 256 blocks = k(32) x dg(8 groups of 32 d)
__global__ void prep_kernel(const float* __restrict__ x1, const float* __restrict__ x2,
                            const float* __restrict__ W,
                            u16* __restrict__ x1f, u16* __restrict__ x2f, u16* __restrict__ Wtf) {
    __shared__ float xs[32 * 260];   // 33.3 KiB staging for W tile
    int bid = blockIdx.x;
    int tid = threadIdx.x;
    if (bid < 2048) {
        const float* src; u16* dst; long f4;
        if (bid < 1024) { src = x1; dst = x1f; f4 = (long)bid * 256 + tid; }
        else            { src = x2; dst = x2f; f4 = (long)(bid - 1024) * 256 + tid; }
        long idx = f4 << 2;
        int mat = (int)(idx >> 16);
        int r = (int)((idx >> 8) & 255);
        int c = (int)(idx & 255);
        float4 v = ((const float4*)src)[f4];
        ushort4 o;
        o.x = f2bf(v.x); o.y = f2bf(v.y); o.z = f2bf(v.z); o.w = f2bf(v.w);
        int rt = r >> 4, ct = c >> 5;
        int lane = (r & 15) | (((c >> 3) & 3) << 4);
        long off = ((long)mat << 16) + (((rt << 3) + ct) << 9) + (lane << 3) + (c & 7);
        *(ushort4*)(dst + off) = o;
        return;
    }
    // ---- W transpose blocks: (k, dg) -> Wt frag-order rows e, cols d
    int wb = bid - 2048;
    int k  = wb >> 3;
    int dg = wb & 7;                     // d in [dg*32, dg*32+32)
    const float* wsrc = W + ((long)k << 16) + ((long)dg << 13);
#pragma unroll
    for (int it = 0; it < 8; ++it) {
        int ch = (it << 8) + tid;        // 2048 float4 chunks (32 rows x 64)
        int row = ch >> 6;
        int col4 = ch & 63;
        float4 v = *(const float4*)(wsrc + (row << 8) + (col4 << 2));
        *(float4*)(xs + row * 260 + (col4 << 2)) = v;
    }
    __syncthreads();
    int e = tid;                         // 0..255
    int rt = e >> 4;
    u16* wdst = Wtf + ((long)k << 16) + ((long)((rt << 3) + dg) << 9);
#pragma unroll
    for (int g = 0; g < 4; ++g) {        // lane-group = dd>>3
        ushort8v pk;
#pragma unroll
        for (int q = 0; q < 8; ++q)
            pk[q] = f2bf(xs[((g << 3) + q) * 260 + e]);
        *(ushort8v*)(wdst + (((e & 15) | (g << 4)) << 3)) = pk;   // 16B coalesced-ish
    }
}

// ---------------- main fused kernel: l-split blocks, FULL-ROW output stores --------
// grid: 2048 = (k 32) x (b 16) x (lq 4), R13-style XCD supertile (8k x 4b x 4lq /slot).
// 512 threads = 8 waves: wm = wid>>1 (m/e-group 0..3), wl = wid&1 (l-group 0..1).
// stage:  x1 l-quarter (frag-order, 32 KiB linear) -> ldsA
// r1[l]:  x1.V1 from ldsA (8 thr/l);  r2[m]: x2.V2 + b from global frags (2 thr/m)
// phase A: T[l 64][e 256] = x1q @ W[k]   (A-frag = Wt[e][d] global, B-frag = x1 LDS;
//          M=e so lane's j-dim = e -> packed ushort4 T-writes, swizzled ldsT)
// phase B: D[m 256][l 64] = x2 @ T^T     (A-frag = x2[m][e] global, B-frag = T LDS;
//          M=m so lane's j-dim = m -> float4 epilogue packing)
// epilogue: +r1[l]+r2[m], relu; chunks f32[32 l][256 m] in ldsA -> every store
//           instruction writes ONE FULL 1KB output row (fill-kernel shape, 1.0x).
__launch_bounds__(512, 4)
__global__ void ntn_main(const u16* __restrict__ x1f, const u16* __restrict__ x2f,
                         const u16* __restrict__ Wtf,
                         const float* __restrict__ V, const float* __restrict__ bb,
                         float* __restrict__ out) {
    __shared__ __align__(16) char ldsA[32768];   // x1 quarter -> epilogue chunks
    __shared__ __align__(16) char ldsT[32768];   // T[l 64][e 256] bf16 swizzled
    __shared__ float r1[64];
    __shared__ float r2[256];

    // supertile decode: 128-block supertiles of 8k x 4b x 4lq per XCD slot
    int bid = blockIdx.x;
    int xcd   = bid & 7;
    int j     = bid >> 3;
    int slot  = j >> 7;
    int inner = j & 127;
    int st    = (slot << 3) | xcd;     // 0..15
    int kg = st >> 2, bg = st & 3;
    int k  = (kg << 3) | (inner >> 4);
    int b  = (bg << 2) | ((inner >> 2) & 3);
    int lq = inner & 3;

    int tid  = threadIdx.x;
    int lane = tid & 63;
    int wid  = tid >> 6;
    int wm = wid >> 1;             // m/e-group 0..3
    int wl = wid & 1;              // l-group 0..1
    int lrow = lane & 15;
    int j4   = (lane >> 4) << 2;
    int lk8  = (lane >> 4) << 3;

    // ---- stage x1 l-quarter: 32 chunks of 1 KiB (frag-order linear)
    {
        const char* src = (const char*)(x1f + ((long)b << 16) + ((long)lq << 14));
#pragma unroll
        for (int it = 0; it < 4; ++it) {
            int chunk = (it << 3) + wid;
            gload_lds16(src + (chunk << 10) + (lane << 4), ldsA + (chunk << 10));
        }
    }
    __syncthreads();   // x1 staged

    // ---- r1[l] = x1[l].V1[k] (8 threads per l, shfl-reduce)
    {
        int ll = tid >> 3;
        int et8 = tid & 7;
        const float* v1p = V + ((long)k << 9) + (et8 << 5);
        float s = 0.f;
#pragma unroll
        for (int eg = 0; eg < 4; ++eg) {
            int lp = (ll & 15) | (eg << 4);
            bf16x8 xv = *(const bf16x8*)(ldsA + ((((ll >> 4) << 3) + et8) << 10) + (lp << 4));
            float4 va = *(const float4*)(v1p + (eg << 3));
            float4 vb = *(const float4*)(v1p + (eg << 3) + 4);
            s += (float)xv[0] * va.x + (float)xv[1] * va.y + (float)xv[2] * va.z + (float)xv[3] * va.w
               + (float)xv[4] * vb.x + (float)xv[5] * vb.y + (float)xv[6] * vb.z + (float)xv[7] * vb.w;
        }
        s += __shfl_xor(s, 1);
        s += __shfl_xor(s, 2);
        s += __shfl_xor(s, 4);
        if ((tid & 7) == 0) r1[ll] = s;
    }

    // ---- r2[m] = x2[m].V2[k] + b[k] (2 threads per m; x2 frags L2-hot via phase B)
    {
        int mm = tid >> 1;
        int eh = tid & 1;
        const u16* x2p = x2f + ((long)b << 16);
        const float* v2p = V + ((long)k << 9) + 256;
        float s = 0.f;
#pragma unroll
        for (int t4 = 0; t4 < 4; ++t4) {
            int et = (eh << 2) + t4;
#pragma unroll
            for (int eg = 0; eg < 4; ++eg) {
                int lp = (mm & 15) | (eg << 4);
                bf16x8 xv = *(const bf16x8*)(x2p + ((((mm >> 4) << 3) + et) << 9) + (lp << 3));
                const float* vv = v2p + (et << 5) + (eg << 3);
                float4 va = *(const float4*)(vv);
                float4 vb = *(const float4*)(vv + 4);
                s += (float)xv[0] * va.x + (float)xv[1] * va.y + (float)xv[2] * va.z + (float)xv[3] * va.w
                   + (float)xv[4] * vb.x + (float)xv[5] * vb.y + (float)xv[6] * vb.z + (float)xv[7] * vb.w;
            }
        }
        s += __shfl_xor(s, 1);
        if (eh == 0) r2[mm] = s + bb[k];
    }

    const f32x4 fz = {0.f, 0.f, 0.f, 0.f};
    f32x4 acc[4][2];
#pragma unroll
    for (int q = 0; q < 4; ++q) { acc[q][0] = fz; acc[q][1] = fz; }

    // ================= phase A: T = x1q @ W[k]  (M=e 16 tiles, N=l 4 tiles, K=d) =====
    {
        const u16* wtp = Wtf + ((long)k << 16);
#pragma unroll
        for (int dt = 0; dt < 8; ++dt) {
            bf16x8 af[4], bfl[2];
#pragma unroll
            for (int q = 0; q < 4; ++q)
                af[q] = *(const bf16x8*)(wtp + (((((wm << 2) + q) << 3) + dt) << 9) + (lane << 3));
#pragma unroll
            for (int p = 0; p < 2; ++p)
                bfl[p] = *(const bf16x8*)(ldsA + ((((((wl << 1) + p) << 3) + dt) << 10) + (lane << 4)));
#pragma unroll
            for (int p = 0; p < 2; ++p)
#pragma unroll
                for (int q = 0; q < 4; ++q)
                    acc[q][p] = __builtin_amdgcn_mfma_f32_16x16x32_bf16(af[q], bfl[p], acc[q][p], 0, 0, 0);
        }
    }
    __syncthreads();   // x1/r1 LDS reads done (ldsA dead until epilogue)

    // ---- write T[l 64][e 256] bf16 (rows 512B), swizzle byte^=((l&7)<<4)
    //      lane holds 4 consecutive e (j-dim) at fixed l -> packed ushort4
#pragma unroll
    for (int q = 0; q < 4; ++q) {
        int e0 = (wm << 6) + (q << 4) + j4;
#pragma unroll
        for (int p = 0; p < 2; ++p) {
            int l = (wl << 5) + (p << 4) + lrow;
            ushort4 pk;
            pk.x = f2bf(acc[q][p][0]);
            pk.y = f2bf(acc[q][p][1]);
            pk.z = f2bf(acc[q][p][2]);
            pk.w = f2bf(acc[q][p][3]);
            *(ushort4*)(ldsT + (l << 9) + ((e0 << 1) ^ ((l & 7) << 4))) = pk;
        }
    }
    __syncthreads();

#pragma unroll
    for (int q = 0; q < 4; ++q) { acc[q][0] = fz; acc[q][1] = fz; }

    // ================= phase B: D[m][l] = x2 @ T^T  (M=m 16 tiles, N=l 4, K=e) =======
    {
        const u16* x2p = x2f + ((long)b << 16);
#pragma unroll
        for (int et = 0; et < 8; ++et) {
            int e = (et << 5) + lk8;
            bf16x8 am[4], tf[2];
#pragma unroll
            for (int q = 0; q < 4; ++q)
                am[q] = *(const bf16x8*)(x2p + (((((wm << 2) + q) << 3) + et) << 9) + (lane << 3));
#pragma unroll
            for (int p = 0; p < 2; ++p) {
                int l = (wl << 5) + (p << 4) + lrow;
                tf[p] = *(const bf16x8*)(ldsT + (l << 9) + ((e << 1) ^ ((l & 7) << 4)));
            }
#pragma unroll
            for (int p = 0; p < 2; ++p)
#pragma unroll
                for (int q = 0; q < 4; ++q)
                    acc[q][p] = __builtin_amdgcn_mfma_f32_16x16x32_bf16(am[q], tf[p], acc[q][p], 0, 0, 0);
        }
    }

    // ================= epilogue: +r1+r2, relu; FULL-ROW stores via ldsA chunks =======
    // lane holds m0 = wm*64+q*16+j4 (+j consecutive m), l = wl*32+p*16+lrow
    {
        float* outp = out + (((long)(b * NK + k)) << 16) + ((long)(lq << 6) << 8);
#pragma unroll
        for (int c = 0; c < 2; ++c) {
            if (wl == c) {
#pragma unroll
                for (int q = 0; q < 4; ++q) {
                    int m0 = (wm << 6) + (q << 4) + j4;
                    float4 rv = *(const float4*)(r2 + m0);
#pragma unroll
                    for (int p = 0; p < 2; ++p) {
                        int row = (p << 4) + lrow;              // 0..31 within chunk
                        float rb = r1[(c << 5) + row];
                        f32x4 v;
                        v[0] = acc[q][p][0] + rb + rv.x;
                        v[1] = acc[q][p][1] + rb + rv.y;
                        v[2] = acc[q][p][2] + rb + rv.z;
                        v[3] = acc[q][p][3] + rb + rv.w;
                        v[0] = v[0] > 0.f ? v[0] : 0.f;
                        v[1] = v[1] > 0.f ? v[1] : 0.f;
                        v[2] = v[2] > 0.f ? v[2] : 0.f;
                        v[3] = v[3] > 0.f ? v[3] : 0.f;
                        *(f32x4*)(ldsA + (row << 10) + ((m0 << 2) ^ ((row & 7) << 4))) = v;
                    }
                }
            }
            __syncthreads();
            // stream chunk: 32 rows x 1KB; each wave-iter writes ONE FULL ROW
#pragma unroll
            for (int it = 0; it < 4; ++it) {
                int g = (it << 9) + tid;
                int row = g >> 6;       // 0..31
                int c4  = g & 63;       // 16B block within 1KB row
                f32x4 v = *(const f32x4*)(ldsA + (row << 10) + ((c4 << 4) ^ ((row & 7) << 4)));
                *(f32x4*)(outp + ((long)((c << 5) + row) << 8) + (c4 << 2)) = v;
            }
            if (c == 0) __syncthreads();
        }
    }
}

extern "C" void kernel_launch(void* const* d_in, const int* in_sizes, int n_in,
                              void* d_out, int out_size, void* d_ws, size_t ws_size,
                              hipStream_t stream) {
    const float* x1 = (const float*)d_in[0];
    const float* x2 = (const float*)d_in[1];
    const float* W  = (const float*)d_in[2];
    const float* V  = (const float*)d_in[3];
    const float* bb = (const float*)d_in[4];
    float* out = (float*)d_out;

    char* ws = (char*)d_ws;
    u16*   x1f  = (u16*)(ws);                               // 2 MiB
    u16*   x2f  = (u16*)(ws + (2l << 20));                  // 2 MiB
    u16*   Wtf  = (u16*)(ws + (4l << 20));                  // 4 MiB

    hipLaunchKernelGGL(prep_kernel, dim3(2304), dim3(256), 0, stream,
                       x1, x2, W, x1f, x2f, Wtf);
    hipLaunchKernelGGL(ntn_main, dim3(2048), dim3(512), 0, stream,
                       x1f, x2f, Wtf, V, bb, out);
}

// Round 18
// 73.570 us; speedup vs baseline: 1.5330x; 1.5330x over previous
//
#include <hip/hip_runtime.h>
#include <hip/hip_bf16.h>

typedef unsigned short u16;
typedef unsigned short ushort8v __attribute__((ext_vector_type(8)));
typedef __bf16 bf16x8 __attribute__((ext_vector_type(8)));
typedef float f32x4 __attribute__((ext_vector_type(4)));

#define NB 16   // batch
#define NK 32   // K slices
#define ND 256  // D
#define NL 256  // L1 == L2

__device__ __forceinline__ u16 f2bf(float f) {
    __hip_bfloat16 h = __float2bfloat16(f);
    return __builtin_bit_cast(u16, h);
}

// async global->LDS, 16B per lane; lds dst = wave-uniform base + lane*16
__device__ __forceinline__ void gload_lds16(const void* g, void* l) {
    __builtin_amdgcn_global_load_lds(
        (const __attribute__((address_space(1))) unsigned int*)g,
        (__attribute__((address_space(3))) unsigned int*)l, 16, 0, 0);
}

// Fragment-order layout for a 256x256 matrix X[r][c] (c = contraction dim):
//   buf[((rt*8 + ct)*64 + lane)*8 + (c&7)], rt=r>>4, ct=c>>5,
//   lane = (r&15) | (((c>>3)&3)<<4)
// => a wave's 16x16x32 MFMA fragment is 1 KiB contiguous; coalesced dwordx4 loads.

// ---------------- prep ----------------
// blocks 0..1023    : x1 f32 -> frag-order bf16 [l][d]
// blocks 1024..2047 : x2 f32 -> frag-order bf16 [m][e]
// blocks 2048..2303 : W  f32 -> frag-order bf16 of W^T ([e][d]) via LDS transpose
__global__ void prep_kernel(const float* __restrict__ x1, const float* __restrict__ x2,
                            const float* __restrict__ W,
                            u16* __restrict__ x1f, u16* __restrict__ x2f, u16* __restrict__ Wtf) {
    __shared__ float xs[32 * 260];
    int bid = blockIdx.x;
    int tid = threadIdx.x;
    if (bid < 2048) {
        const float* src; u16* dst; long f4;
        if (bid < 1024) { src = x1; dst = x1f; f4 = (long)bid * 256 + tid; }
        else            { src = x2; dst = x2f; f4 = (long)(bid - 1024) * 256 + tid; }
        long idx = f4 << 2;
        int mat = (int)(idx >> 16);
        int r = (int)((idx >> 8) & 255);
        int c = (int)(idx & 255);
        float4 v = ((const float4*)src)[f4];
        ushort4 o;
        o.x = f2bf(v.x); o.y = f2bf(v.y); o.z = f2bf(v.z); o.w = f2bf(v.w);
        int rt = r >> 4, ct = c >> 5;
        int lane = (r & 15) | (((c >> 3) & 3) << 4);
        long off = ((long)mat << 16) + (((rt << 3) + ct) << 9) + (lane << 3) + (c & 7);
        *(ushort4*)(dst + off) = o;
        return;
    }
    int wb = bid - 2048;
    int k  = wb >> 3;
    int dg = wb & 7;
    const float* wsrc = W + ((long)k << 16) + ((long)dg << 13);
#pragma unroll
    for (int it = 0; it < 8; ++it) {
        int ch = (it << 8) + tid;
        int row = ch >> 6;
        int col4 = ch & 63;
        float4 v = *(const float4*)(wsrc + (row << 8) + (col4 << 2));
        *(float4*)(xs + row * 260 + (col4 << 2)) = v;
    }
    __syncthreads();
    int e = tid;
    int rt = e >> 4;
    u16* wdst = Wtf + ((long)k << 16) + ((long)((rt << 3) + dg) << 9);
#pragma unroll
    for (int g = 0; g < 4; ++g) {
        ushort8v pk;
#pragma unroll
        for (int q = 0; q < 8; ++q)
            pk[q] = f2bf(xs[((g << 3) + q) * 260 + e]);
        *(ushort8v*)(wdst + (((e & 15) | (g << 4)) << 3)) = pk;
    }
}

// ---------------- main: l-split blocks, full-row stores, pipelined frag loads ------
// grid: 2048 = (k 32) x (b 16) x (lq 4), R13-style XCD supertile.
// phase A: T'[l 64][e 256] = x1q @ W[k] (+V2 fold)  -> bilinear+lin2 emerge in B
// phase B: D[m 256][l 64] = x2 @ T'^T   (+r1[l] = x1.V1+b fold in epilogue)
// both phases: explicit 2-stage register pipeline (load dt+1 before dt's MFMAs);
// first global frags issued BEFORE the preceding barrier (latency hidden).
// epilogue: +r1, relu; f32[32 l][256 m] LDS chunks -> full 1KB-row stores (1.0x).
__launch_bounds__(512, 4)
__global__ void ntn_main(const u16* __restrict__ x1f, const u16* __restrict__ x2f,
                         const u16* __restrict__ Wtf,
                         const float* __restrict__ V, const float* __restrict__ bb,
                         float* __restrict__ out) {
    __shared__ __align__(16) char ldsA[32768];   // x1 quarter -> epilogue chunks
    __shared__ __align__(16) char ldsT[32768];   // T'[l 64][e 256] bf16 swizzled
    __shared__ float r1[64];

    int bid = blockIdx.x;
    int xcd   = bid & 7;
    int j     = bid >> 3;
    int slot  = j >> 7;
    int inner = j & 127;
    int st    = (slot << 3) | xcd;
    int kg = st >> 2, bg = st & 3;
    int k  = (kg << 3) | (inner >> 4);
    int b  = (bg << 2) | ((inner >> 2) & 3);
    int lq = inner & 3;

    int tid  = threadIdx.x;
    int lane = tid & 63;
    int wid  = tid >> 6;
    int wm = wid >> 1;             // m/e-group 0..3
    int wl = wid & 1;              // l-group 0..1
    int lrow = lane & 15;
    int j4   = (lane >> 4) << 2;
    int lk8  = (lane >> 4) << 3;

    const u16* wtp = Wtf + ((long)k << 16);
    const u16* x2p = x2f + ((long)b << 16);

    // ---- stage x1 l-quarter (async) + prefetch phase A's first W^T frags
    {
        const char* src = (const char*)(x1f + ((long)b << 16) + ((long)lq << 14));
#pragma unroll
        for (int it = 0; it < 4; ++it) {
            int chunk = (it << 3) + wid;
            gload_lds16(src + (chunk << 10) + (lane << 4), ldsA + (chunk << 10));
        }
    }
    bf16x8 afC[4], afN[4];
#pragma unroll
    for (int q = 0; q < 4; ++q)
        afC[q] = *(const bf16x8*)(wtp + ((((wm << 2) + q) << 3) << 9) + (lane << 3));
    float bk = bb[k];
    __syncthreads();   // x1 staged (af prefetch latency hidden under stage drain)

    // ---- r1[l] = x1[l].V1[k] + b[k] (8 threads per l, shfl-reduce)
    {
        int ll = tid >> 3;
        int et8 = tid & 7;
        const float* v1p = V + ((long)k << 9) + (et8 << 5);
        float s = 0.f;
#pragma unroll
        for (int eg = 0; eg < 4; ++eg) {
            int lp = (ll & 15) | (eg << 4);
            bf16x8 xv = *(const bf16x8*)(ldsA + ((((ll >> 4) << 3) + et8) << 10) + (lp << 4));
            float4 va = *(const float4*)(v1p + (eg << 3));
            float4 vb = *(const float4*)(v1p + (eg << 3) + 4);
            s += (float)xv[0] * va.x + (float)xv[1] * va.y + (float)xv[2] * va.z + (float)xv[3] * va.w
               + (float)xv[4] * vb.x + (float)xv[5] * vb.y + (float)xv[6] * vb.z + (float)xv[7] * vb.w;
        }
        s += __shfl_xor(s, 1);
        s += __shfl_xor(s, 2);
        s += __shfl_xor(s, 4);
        if ((tid & 7) == 0) r1[ll] = s + bk;
    }

    const f32x4 fz = {0.f, 0.f, 0.f, 0.f};
    f32x4 acc[4][2];
#pragma unroll
    for (int q = 0; q < 4; ++q) { acc[q][0] = fz; acc[q][1] = fz; }

    // ================= phase A: T' = x1q @ W[k]  (M=e, N=l, K=d), pipelined =========
    {
        bf16x8 bflC[2], bflN[2];
#pragma unroll
        for (int p = 0; p < 2; ++p)
            bflC[p] = *(const bf16x8*)(ldsA + (((((wl << 1) + p) << 3) << 10) + (lane << 4)));
#pragma unroll
        for (int dt = 0; dt < 8; ++dt) {
            if (dt < 7) {
#pragma unroll
                for (int q = 0; q < 4; ++q)
                    afN[q] = *(const bf16x8*)(wtp + (((((wm << 2) + q) << 3) + dt + 1) << 9) + (lane << 3));
#pragma unroll
                for (int p = 0; p < 2; ++p)
                    bflN[p] = *(const bf16x8*)(ldsA + ((((((wl << 1) + p) << 3) + dt + 1) << 10) + (lane << 4)));
            }
#pragma unroll
            for (int p = 0; p < 2; ++p)
#pragma unroll
                for (int q = 0; q < 4; ++q)
                    acc[q][p] = __builtin_amdgcn_mfma_f32_16x16x32_bf16(afC[q], bflC[p], acc[q][p], 0, 0, 0);
#pragma unroll
            for (int q = 0; q < 4; ++q) afC[q] = afN[q];
#pragma unroll
            for (int p = 0; p < 2; ++p) bflC[p] = bflN[p];
        }
    }
    __syncthreads();   // x1/r1 LDS reads done

    // ---- write T'[l][e] bf16 swizzled; V2[e] added in f32 (lin2 fold); prefetch x2
    {
        const float* v2base = V + ((long)k << 9) + 256;
#pragma unroll
        for (int q = 0; q < 4; ++q) {
            int e0 = (wm << 6) + (q << 4) + j4;
            float4 v2q = *(const float4*)(v2base + e0);
#pragma unroll
            for (int p = 0; p < 2; ++p) {
                int l = (wl << 5) + (p << 4) + lrow;
                ushort4 pk;
                pk.x = f2bf(acc[q][p][0] + v2q.x);
                pk.y = f2bf(acc[q][p][1] + v2q.y);
                pk.z = f2bf(acc[q][p][2] + v2q.z);
                pk.w = f2bf(acc[q][p][3] + v2q.w);
                *(ushort4*)(ldsT + (l << 9) + ((e0 << 1) ^ ((l & 7) << 4))) = pk;
            }
        }
    }
    bf16x8 amC[4], amN[4];
#pragma unroll
    for (int q = 0; q < 4; ++q)
        amC[q] = *(const bf16x8*)(x2p + ((((wm << 2) + q) << 3) << 9) + (lane << 3));
    __syncthreads();   // T' visible (am prefetch latency hidden under barrier)

#pragma unroll
    for (int q = 0; q < 4; ++q) { acc[q][0] = fz; acc[q][1] = fz; }

    // ================= phase B: D[m][l] = x2 @ T'^T  (M=m, N=l, K=e), pipelined ======
    {
        bf16x8 tfC[2], tfN[2];
#pragma unroll
        for (int p = 0; p < 2; ++p) {
            int l = (wl << 5) + (p << 4) + lrow;
            tfC[p] = *(const bf16x8*)(ldsT + (l << 9) + ((lk8 << 1) ^ ((l & 7) << 4)));
        }
#pragma unroll
        for (int et = 0; et < 8; ++et) {
            if (et < 7) {
                int e = ((et + 1) << 5) + lk8;
#pragma unroll
                for (int q = 0; q < 4; ++q)
                    amN[q] = *(const bf16x8*)(x2p + (((((wm << 2) + q) << 3) + et + 1) << 9) + (lane << 3));
#pragma unroll
                for (int p = 0; p < 2; ++p) {
                    int l = (wl << 5) + (p << 4) + lrow;
                    tfN[p] = *(const bf16x8*)(ldsT + (l << 9) + ((e << 1) ^ ((l & 7) << 4)));
                }
            }
#pragma unroll
            for (int p = 0; p < 2; ++p)
#pragma unroll
                for (int q = 0; q < 4; ++q)
                    acc[q][p] = __builtin_amdgcn_mfma_f32_16x16x32_bf16(amC[q], tfC[p], acc[q][p], 0, 0, 0);
#pragma unroll
            for (int q = 0; q < 4; ++q) amC[q] = amN[q];
#pragma unroll
            for (int p = 0; p < 2; ++p) tfC[p] = tfN[p];
        }
    }

    // ================= epilogue: +r1[l], relu; FULL-ROW stores via ldsA chunks =======
    {
        float* outp = out + (((long)(b * NK + k)) << 16) + ((long)(lq << 6) << 8);
#pragma unroll
        for (int c = 0; c < 2; ++c) {
            if (wl == c) {
#pragma unroll
                for (int q = 0; q < 4; ++q) {
                    int m0 = (wm << 6) + (q << 4) + j4;
#pragma unroll
                    for (int p = 0; p < 2; ++p) {
                        int row = (p << 4) + lrow;              // 0..31 within chunk
                        float rb = r1[(c << 5) + row];
                        f32x4 v;
                        v[0] = acc[q][p][0] + rb;
                        v[1] = acc[q][p][1] + rb;
                        v[2] = acc[q][p][2] + rb;
                        v[3] = acc[q][p][3] + rb;
                        v[0] = v[0] > 0.f ? v[0] : 0.f;
                        v[1] = v[1] > 0.f ? v[1] : 0.f;
                        v[2] = v[2] > 0.f ? v[2] : 0.f;
                        v[3] = v[3] > 0.f ? v[3] : 0.f;
                        *(f32x4*)(ldsA + (row << 10) + ((m0 << 2) ^ ((row & 7) << 4))) = v;
                    }
                }
            }
            __syncthreads();
            // stream chunk: 32 rows x 1KB; each wave-iter writes ONE FULL ROW
#pragma unroll
            for (int it = 0; it < 4; ++it) {
                int g = (it << 9) + tid;
                int row = g >> 6;       // 0..31
                int c4  = g & 63;       // 16B block within 1KB row
                f32x4 v = *(const f32x4*)(ldsA + (row << 10) + ((c4 << 4) ^ ((row & 7) << 4)));
                *(f32x4*)(outp + ((long)((c << 5) + row) << 8) + (c4 << 2)) = v;
            }
            if (c == 0) __syncthreads();
        }
    }
}

extern "C" void kernel_launch(void* const* d_in, const int* in_sizes, int n_in,
                              void* d_out, int out_size, void* d_ws, size_t ws_size,
                              hipStream_t stream) {
    const float* x1 = (const float*)d_in[0];
    const float* x2 = (const float*)d_in[1];
    const float* W  = (const float*)d_in[2];
    const float* V  = (const float*)d_in[3];
    const float* bb = (const float*)d_in[4];
    float* out = (float*)d_out;

    char* ws = (char*)d_ws;
    u16*   x1f  = (u16*)(ws);                               // 2 MiB
    u16*   x2f  = (u16*)(ws + (2l << 20));                  // 2 MiB
    u16*   Wtf  = (u16*)(ws + (4l << 20));                  // 4 MiB

    hipLaunchKernelGGL(prep_kernel, dim3(2304), dim3(256), 0, stream,
                       x1, x2, W, x1f, x2f, Wtf);
    hipLaunchKernelGGL(ntn_main, dim3(2048), dim3(512), 0, stream,
                       x1f, x2f, Wtf, V, bb, out);
}